// Round 8
// baseline (131.159 us; speedup 1.0000x reference)
//
#include <hip/hip_runtime.h>
#include <hip/hip_bf16.h>

#define D 96
#define LN_EPS 1e-5f
#define CHUNK 1024          // edges per partition block
#define BCAP 8192           // per-bucket fixed capacity in part[] (mean 4096, +64 sigma)
#define BCAPP (BCAP + 1792) // per-bucket region in csr_src (pad-8 slack = 7*256)

typedef unsigned short ushort_t;
typedef __attribute__((ext_vector_type(8))) short short8;
typedef __attribute__((ext_vector_type(4))) float f32x4;

__device__ __forceinline__ ushort_t f2bf(float f) {
    unsigned u = __float_as_uint(f);
    u += 0x7FFF + ((u >> 16) & 1);          // round-to-nearest-even
    return (ushort_t)(u >> 16);
}
__device__ __forceinline__ float blo(unsigned v) {   // low bf16 -> f32
    return __uint_as_float(v << 16);
}
__device__ __forceinline__ float bhi(unsigned v) {   // high bf16 -> f32
    return __uint_as_float(v & 0xffff0000u);
}
__device__ __forceinline__ unsigned pack2(float lo, float hi) {
    return ((unsigned)f2bf(hi) << 16) | (unsigned)f2bf(lo);
}

// ---------------------------------------------------------------------------
// Init (1 block): edge dtype detect, gcur = b*BCAP, zero hs sentinel rows.
// int64 edges => every odd 32-bit word of first 256 words is zero.
// ---------------------------------------------------------------------------
__global__ __launch_bounds__(256) void k_init(const unsigned* __restrict__ w,
                                              int* __restrict__ flag,
                                              int* __restrict__ gcur,
                                              unsigned* __restrict__ hsA,
                                              unsigned* __restrict__ hsB,
                                              int N, int nbuk) {
    __shared__ int anynz;
    int t = threadIdx.x;
    if (t == 0) anynz = 0;
    __syncthreads();
    if ((t & 1) && w[t] != 0) anynz = 1;
    if (t < nbuk) gcur[t] = t * BCAP;
    if (t < 32) hsA[(size_t)N * 32 + t] = 0;   // sentinel row
    if (t < 16) hsB[(size_t)N * 16 + t] = 0;
    __syncthreads();
    if (t == 0) *flag = (anynz == 0) ? 1 : 0;
}

__device__ __forceinline__ int load_idx(const void* eb, int is64, long long pos) {
    if (is64) return (int)((const long long*)eb)[pos];
    return ((const int*)eb)[pos];
}

// ---------------------------------------------------------------------------
// Fused dispatch: gemm-type blocks compute unscaled layer-1 GEMM
// (hs = bf16(x @ W0), f32->bf16 convert + W transpose during LDS staging);
// bfill-type blocks partition edges into fixed-capacity bucket regions.
// Blocks interleaved by parity for concurrent execution.
// mfma_f32_16x16x32_bf16: A[row=l&15][k=(l>>4)*8+j], B[k][col=l&15],
// D[row=(l>>4)*4+reg][col=l&15] (m89-verified). LDS rows padded to 104
// elems (208B) -> 2-way conflicts only (free).
// ---------------------------------------------------------------------------
union Smem1 {
    struct { ushort_t As[64][104]; ushort_t Bs[96][104]; } g;
    struct { int hist[2][256]; int cur[2][256]; } b;
};

__global__ __launch_bounds__(256) void k_fused1(const float* __restrict__ X,
                                                const float* __restrict__ W0,
                                                ushort_t* __restrict__ HsA,
                                                ushort_t* __restrict__ HsB,
                                                int N, int nbG,
                                                const void* __restrict__ eb,
                                                const int* __restrict__ flag,
                                                int* __restrict__ gcur,
                                                unsigned* __restrict__ part, int E,
                                                int NBLK) {
    __shared__ Smem1 u;
    int t = threadIdx.x;
    int bid = blockIdx.x;
    int mn = min(nbG, NBLK);
    int isG, idx;
    if (bid < 2 * mn) { isG = !(bid & 1); idx = bid >> 1; }
    else {
        int r = bid - 2 * mn;
        if (nbG > NBLK) { isG = 1; idx = mn + r; }
        else            { isG = 0; idx = mn + r; }
    }

    if (isG) {
        // ---- layer-1 GEMM block (rows idx*64 .. +63), unscaled output ----
        int row0 = idx * 64;
        const float4* X4 = (const float4*)X;
        #pragma unroll
        for (int i = 0; i < 6; ++i) {             // 64x24 float4 = 1536
            int id2 = t + i * 256;
            int r = id2 / 24, c4 = id2 % 24;
            float4 v = make_float4(0.f, 0.f, 0.f, 0.f);
            if (row0 + r < N) v = X4[(size_t)(row0 + r) * 24 + c4];
            ushort4 o;
            o.x = f2bf(v.x); o.y = f2bf(v.y); o.z = f2bf(v.z); o.w = f2bf(v.w);
            *(ushort4*)&u.g.As[r][c4 * 4] = o;
        }
        const float4* W4 = (const float4*)W0;
        #pragma unroll
        for (int i = 0; i < 9; ++i) {             // 96x24 float4 = 2304
            int id2 = t + i * 256;
            int k = id2 / 24, c4 = id2 % 24;
            float4 v = W4[id2];                   // W[k][4c4..4c4+3]
            u.g.Bs[c4 * 4 + 0][k] = f2bf(v.x);    // transpose-convert
            u.g.Bs[c4 * 4 + 1][k] = f2bf(v.y);
            u.g.Bs[c4 * 4 + 2][k] = f2bf(v.z);
            u.g.Bs[c4 * 4 + 3][k] = f2bf(v.w);
        }
        __syncthreads();

        int w = t >> 6, l = t & 63;
        int lr = l & 15, lq = l >> 4;
        f32x4 acc[6];
        #pragma unroll
        for (int c = 0; c < 6; ++c) acc[c] = (f32x4){0.f, 0.f, 0.f, 0.f};
        #pragma unroll
        for (int q = 0; q < 3; ++q) {
            short8 af = *(const short8*)&u.g.As[w * 16 + lr][q * 32 + lq * 8];
            #pragma unroll
            for (int c = 0; c < 6; ++c) {
                short8 bf = *(const short8*)&u.g.Bs[c * 16 + lr][q * 32 + lq * 8];
                acc[c] = __builtin_amdgcn_mfma_f32_16x16x32_bf16(af, bf, acc[c], 0, 0, 0);
            }
        }
        int rbase = row0 + w * 16 + lq * 4;
        #pragma unroll
        for (int r = 0; r < 4; ++r) {
            int gr = rbase + r;
            if (gr < N) {
                ushort_t* oA = HsA + (size_t)gr * 64 + lr;
                ushort_t* oB = HsB + (size_t)gr * 32 + lr;
                #pragma unroll
                for (int c = 0; c < 4; ++c) oA[c * 16] = f2bf(acc[c][r]);
                #pragma unroll
                for (int c = 4; c < 6; ++c) oB[(c - 4) * 16] = f2bf(acc[c][r]);
            }
        }
    } else {
        // ---- edge-partition block (bucket = dst >> 8) ----
        int half = t >> 7;
        u.b.hist[0][t] = 0; u.b.hist[1][t] = 0;
        __syncthreads();
        int is64 = *flag;
        long long base = (long long)idx * CHUNK;
        int sv[CHUNK / 256];
        int dv[CHUNK / 256];
        #pragma unroll
        for (int i = 0; i < CHUNK / 256; ++i) {
            long long e = base + t + (long long)i * 256;
            if (e < E) {
                sv[i] = load_idx(eb, is64, e);
                dv[i] = load_idx(eb, is64, (long long)E + e);
                atomicAdd(&u.b.hist[half][dv[i] >> 8], 1);
            } else dv[i] = -1;
        }
        __syncthreads();
        int h0 = u.b.hist[0][t], tot = h0 + u.b.hist[1][t];
        int b0 = 0;
        if (tot > 0) b0 = atomicAdd(&gcur[t], tot);
        u.b.cur[0][t] = b0;
        u.b.cur[1][t] = b0 + h0;
        __syncthreads();
        #pragma unroll
        for (int i = 0; i < CHUNK / 256; ++i) {
            if (dv[i] >= 0) {
                int b = dv[i] >> 8;
                int pos = atomicAdd(&u.b.cur[half][b], 1);
                part[pos] = ((unsigned)sv[i] << 8) | (unsigned)(dv[i] & 255);
            }
        }
    }
}

// ---------------------------------------------------------------------------
// Per-bucket CSR finalize, per-node padding to x8 (sentinel = N), then
// in-place scale of this bucket's 256 hs rows by dis (bf16).
// Bucket b: part region [b*BCAP, gcur[b]); csr region starts at b*BCAPP.
// ---------------------------------------------------------------------------
__global__ __launch_bounds__(256) void k_build(const unsigned* __restrict__ part,
                                               const int* __restrict__ gcur,
                                               int2* __restrict__ rr,
                                               int* __restrict__ csr_src,
                                               float* __restrict__ dis,
                                               unsigned* __restrict__ hsA,
                                               unsigned* __restrict__ hsB,
                                               int N) {
    __shared__ int bins[2][256];
    __shared__ int cur[2][256];
    __shared__ int sh[256];
    __shared__ float disl[256];
    int t = threadIdx.x;
    int b = blockIdx.x;
    int half = t >> 7;
    int beg = b * BCAP, end = gcur[b];
    bins[0][t] = 0; bins[1][t] = 0;
    __syncthreads();
    for (int i = beg + t; i < end; i += 256)
        atomicAdd(&bins[half][part[i] & 255u], 1);
    __syncthreads();
    int d0 = bins[0][t];
    int deg = d0 + bins[1][t];
    int pdeg = (deg + 7) & ~7;
    sh[t] = pdeg;
    __syncthreads();
    for (int off = 1; off < 256; off <<= 1) {
        int x = (t >= off) ? sh[t - off] : 0;
        __syncthreads();
        sh[t] += x;
        __syncthreads();
    }
    int mybeg = b * BCAPP + (sh[t] - pdeg);
    int node = b * 256 + t;
    float dv = rsqrtf((float)(deg + 1));
    disl[t] = dv;
    if (node < N) {
        rr[node] = make_int2(mybeg, mybeg + pdeg);
        dis[node] = dv;
    }
    cur[0][t] = mybeg;
    cur[1][t] = mybeg + d0;
    __syncthreads();
    for (int i = beg + t; i < end; i += 256) {
        unsigned p = part[i];
        int pos = atomicAdd(&cur[half][p & 255u], 1);
        csr_src[pos] = (int)(p >> 8);
    }
    for (int k = deg; k < pdeg; ++k) csr_src[mybeg + k] = N;  // sentinels
    __syncthreads();
    // in-place scale hs rows of this bucket by dis
    int base = b * 256;
    #pragma unroll 4
    for (int i = t; i < 256 * 32; i += 256) {
        int nd = base + (i >> 5);
        if (nd < N) {
            float dn = disl[i >> 5];
            size_t p = (size_t)nd * 32 + (i & 31);
            unsigned v = hsA[p];
            hsA[p] = pack2(blo(v) * dn, bhi(v) * dn);
        }
    }
    #pragma unroll 4
    for (int i = t; i < 256 * 16; i += 256) {
        int nd = base + (i >> 4);
        if (nd < N) {
            float dn = disl[i >> 4];
            size_t p = (size_t)nd * 16 + (i & 15);
            unsigned v = hsB[p];
            hsB[p] = pack2(blo(v) * dn, bhi(v) * dn);
        }
    }
}

// ---------------------------------------------------------------------------
// Layer-2 GEMM: hs = bf16( h1 @ W1 ), split-bf16 input (h1A [N][64],
// h1B [N][32] ushort), W1 f32 transposed-converted during staging.
// h1 is dis-premultiplied, so output is already correctly scaled.
// ---------------------------------------------------------------------------
__global__ __launch_bounds__(256) void k_gemm2(const ushort_t* __restrict__ A0,
                                               const ushort_t* __restrict__ A1,
                                               const float* __restrict__ W1,
                                               ushort_t* __restrict__ HsA,
                                               ushort_t* __restrict__ HsB, int N) {
    __shared__ ushort_t As[64][104];
    __shared__ ushort_t Bs[96][104];
    int t = threadIdx.x;
    int row0 = blockIdx.x * 64;

    #pragma unroll
    for (int i = 0; i < 3; ++i) {                 // 64x12 short8 = 768
        int idx = t + i * 256;
        int r = idx / 12, c8 = idx % 12;
        short8 v = {0, 0, 0, 0, 0, 0, 0, 0};
        if (row0 + r < N) {
            if (c8 < 8) v = *(const short8*)(A0 + (size_t)(row0 + r) * 64 + c8 * 8);
            else        v = *(const short8*)(A1 + (size_t)(row0 + r) * 32 + (c8 - 8) * 8);
        }
        *(short8*)&As[r][c8 * 8] = v;
    }
    const float4* W4 = (const float4*)W1;
    #pragma unroll
    for (int i = 0; i < 9; ++i) {                 // 96x24 float4 = 2304
        int idx = t + i * 256;
        int k = idx / 24, c4 = idx % 24;
        float4 v = W4[idx];
        Bs[c4 * 4 + 0][k] = f2bf(v.x);
        Bs[c4 * 4 + 1][k] = f2bf(v.y);
        Bs[c4 * 4 + 2][k] = f2bf(v.z);
        Bs[c4 * 4 + 3][k] = f2bf(v.w);
    }
    __syncthreads();

    int w = t >> 6, l = t & 63;
    int lr = l & 15, lq = l >> 4;
    f32x4 acc[6];
    #pragma unroll
    for (int c = 0; c < 6; ++c) acc[c] = (f32x4){0.f, 0.f, 0.f, 0.f};
    #pragma unroll
    for (int q = 0; q < 3; ++q) {
        short8 af = *(const short8*)&As[w * 16 + lr][q * 32 + lq * 8];
        #pragma unroll
        for (int c = 0; c < 6; ++c) {
            short8 bf = *(const short8*)&Bs[c * 16 + lr][q * 32 + lq * 8];
            acc[c] = __builtin_amdgcn_mfma_f32_16x16x32_bf16(af, bf, acc[c], 0, 0, 0);
        }
    }
    int rbase = row0 + w * 16 + lq * 4;
    #pragma unroll
    for (int r = 0; r < 4; ++r) {
        int gr = rbase + r;
        if (gr < N) {
            ushort_t* oA = HsA + (size_t)gr * 64 + lr;
            ushort_t* oB = HsB + (size_t)gr * 32 + lr;
            #pragma unroll
            for (int c = 0; c < 4; ++c) oA[c * 16] = f2bf(acc[c][r]);
            #pragma unroll
            for (int c = 4; c < 6; ++c) oB[(c - 4) * 16] = f2bf(acc[c][r]);
        }
    }
}

// ---------------------------------------------------------------------------
// Fused aggregate + bias + tanh + LayerNorm + affine; split-hs gathers.
// 32-lane group per node. hs rows are dis-prescaled. BF16OUT additionally
// premultiplies the output by dis[node] (prepares layer-2 GEMM input).
// Edge runs padded to x8 with sentinel row N (zeros); branch-free bursts.
// ---------------------------------------------------------------------------
template<bool BF16OUT>
__global__ __launch_bounds__(256) void k_agg_ln(const unsigned* __restrict__ hA32,
                                                const unsigned* __restrict__ hB32,
                                                const int2* __restrict__ rr,
                                                const int* __restrict__ csr_src,
                                                const float* __restrict__ dis,
                                                const float* __restrict__ b,
                                                const float* __restrict__ g,
                                                const float* __restrict__ be,
                                                void* __restrict__ outA,
                                                void* __restrict__ outB, int N) {
    int node = blockIdx.x * 8 + (threadIdx.x >> 5);
    int lane = threadIdx.x & 31;
    if (node >= N) return;

    float a0, a1, c0 = 0.f, c1 = 0.f;
    {
        unsigned v = hA32[(size_t)node * 32 + lane];
        a0 = blo(v); a1 = bhi(v);
        if (lane < 16) {
            unsigned uu = hB32[(size_t)node * 16 + lane];
            c0 = blo(uu); c1 = bhi(uu);
        }
    }

    int2 r = rr[node];
    int beg = r.x, end = r.y;
    int lsel = lane >> 4;
    int lb = lane & 15;
    for (int cb = beg; cb < end; cb += 32) {
        int m = min(32, end - cb);
        int e = cb + lane;
        int sreg = (e < end) ? csr_src[e] : (int)N;
        for (int j = 0; j < m; j += 8) {
            int s0 = __shfl(sreg, j, 32);
            int s1 = __shfl(sreg, j + 1, 32);
            int s2 = __shfl(sreg, j + 2, 32);
            int s3 = __shfl(sreg, j + 3, 32);
            int s4 = __shfl(sreg, j + 4, 32);
            int s5 = __shfl(sreg, j + 5, 32);
            int s6 = __shfl(sreg, j + 6, 32);
            int s7 = __shfl(sreg, j + 7, 32);
            int p0 = __shfl(sreg, j + lsel, 32);
            int p1 = __shfl(sreg, j + 2 + lsel, 32);
            int p2 = __shfl(sreg, j + 4 + lsel, 32);
            int p3 = __shfl(sreg, j + 6 + lsel, 32);
            unsigned v0 = hA32[s0 * 32 + lane];
            unsigned v1 = hA32[s1 * 32 + lane];
            unsigned v2 = hA32[s2 * 32 + lane];
            unsigned v3 = hA32[s3 * 32 + lane];
            unsigned v4 = hA32[s4 * 32 + lane];
            unsigned v5 = hA32[s5 * 32 + lane];
            unsigned v6 = hA32[s6 * 32 + lane];
            unsigned v7 = hA32[s7 * 32 + lane];
            unsigned w0 = hB32[p0 * 16 + lb];
            unsigned w1 = hB32[p1 * 16 + lb];
            unsigned w2 = hB32[p2 * 16 + lb];
            unsigned w3 = hB32[p3 * 16 + lb];
            a0 += blo(v0) + blo(v1) + blo(v2) + blo(v3)
                + blo(v4) + blo(v5) + blo(v6) + blo(v7);
            a1 += bhi(v0) + bhi(v1) + bhi(v2) + bhi(v3)
                + bhi(v4) + bhi(v5) + bhi(v6) + bhi(v7);
            c0 += blo(w0) + blo(w1) + blo(w2) + blo(w3);
            c1 += bhi(w0) + bhi(w1) + bhi(w2) + bhi(w3);
        }
    }

    c0 += __shfl_xor(c0, 16, 32);
    c1 += __shfl_xor(c1, 16, 32);

    float dn = dis[node];
    float2 b01 = ((const float2*)b)[lane];
    a0 = tanhf(fmaf(dn, a0, b01.x));
    a1 = tanhf(fmaf(dn, a1, b01.y));
    float s1 = a0 + a1;
    float s2 = a0 * a0 + a1 * a1;
    float a2 = 0.f, a3 = 0.f;
    if (lane < 16) {
        float2 b23 = ((const float2*)b)[32 + lane];
        a2 = tanhf(fmaf(dn, c0, b23.x));
        a3 = tanhf(fmaf(dn, c1, b23.y));
        s1 += a2 + a3;
        s2 += a2 * a2 + a3 * a3;
    }
    #pragma unroll
    for (int off = 16; off >= 1; off >>= 1) {
        s1 += __shfl_xor(s1, off, 32);
        s2 += __shfl_xor(s2, off, 32);
    }
    float mu = s1 * (1.f / 96.f);
    float var = s2 * (1.f / 96.f) - mu * mu;
    float inv = rsqrtf(var + LN_EPS);

    float2 g01 = ((const float2*)g)[lane];
    float2 e01 = ((const float2*)be)[lane];
    float r0 = (a0 - mu) * inv * g01.x + e01.x;
    float r1 = (a1 - mu) * inv * g01.y + e01.y;
    if (BF16OUT) {
        ((unsigned*)outA)[(size_t)node * 32 + lane] = pack2(r0 * dn, r1 * dn);
        if (lane < 16) {
            float2 g23 = ((const float2*)g)[32 + lane];
            float2 e23 = ((const float2*)be)[32 + lane];
            float r2 = ((a2 - mu) * inv * g23.x + e23.x) * dn;
            float r3 = ((a3 - mu) * inv * g23.y + e23.y) * dn;
            ((unsigned*)outB)[(size_t)node * 16 + lane] = pack2(r2, r3);
        }
    } else {
        float2* o2 = (float2*)((float*)outA + (size_t)node * D);
        o2[lane] = make_float2(r0, r1);
        if (lane < 16) {
            float2 g23 = ((const float2*)g)[32 + lane];
            float2 e23 = ((const float2*)be)[32 + lane];
            o2[32 + lane] = make_float2((a2 - mu) * inv * g23.x + e23.x,
                                        (a3 - mu) * inv * g23.y + e23.y);
        }
    }
}

// ---------------------------------------------------------------------------
extern "C" void kernel_launch(void* const* d_in, const int* in_sizes, int n_in,
                              void* d_out, int out_size, void* d_ws, size_t ws_size,
                              hipStream_t stream) {
    const float* x  = (const float*)d_in[0];
    const void*  eb = d_in[1];
    const float* W0 = (const float*)d_in[2];
    const float* b0 = (const float*)d_in[3];
    const float* g0 = (const float*)d_in[4];
    const float* be0 = (const float*)d_in[5];
    const float* W1 = (const float*)d_in[6];
    const float* b1 = (const float*)d_in[7];
    const float* g1 = (const float*)d_in[8];
    const float* be1 = (const float*)d_in[9];

    const int N = in_sizes[0] / D;
    const int E = in_sizes[1] / 2;
    const int NBUK = (N + 255) >> 8;
    const int NBLK = (E + CHUNK - 1) / CHUNK;

    auto al = [](size_t v) { return (v + 255) & ~(size_t)255; };
    char* w = (char*)d_ws;
    size_t off = 0;
    int* flag = (int*)(w + off);          off = al(off + 4);
    int* gcur = (int*)(w + off);          off = al(off + 256 * 4);
    int2* rr = (int2*)(w + off);          off = al(off + (size_t)N * 8);
    float* dis = (float*)(w + off);       off = al(off + (size_t)N * 4);
    int* csr_src = (int*)(w + off);       off = al(off + ((size_t)NBUK * BCAPP + 64) * 4);
    unsigned* part = (unsigned*)(w + off); off = al(off + ((size_t)NBUK * BCAP + BCAP) * 4);
    unsigned* hsA = (unsigned*)(w + off); off = al(off + ((size_t)N + 1) * 128);
    unsigned* hsB = (unsigned*)(w + off); off = al(off + ((size_t)N + 1) * 64);
    unsigned* h1A = (unsigned*)(w + off); off = al(off + (size_t)N * 128);
    unsigned* h1B = (unsigned*)(w + off); off = al(off + (size_t)N * 64);
    float* outf = (float*)d_out;

    const int nbG = (N + 63) / 64;
    const int nbA = (N + 7) / 8;

    k_init<<<1, 256, 0, stream>>>((const unsigned*)eb, flag, gcur, hsA, hsB, N, NBUK);
    // layer-1 GEMM (unscaled)  ||  edge partition — one fused dispatch
    k_fused1<<<nbG + NBLK, 256, 0, stream>>>(x, W0, (ushort_t*)hsA, (ushort_t*)hsB,
                                             N, nbG, eb, flag, gcur, part, E, NBLK);
    // CSR finalize + in-place dis-scale of hs
    k_build<<<NBUK, 256, 0, stream>>>(part, gcur, rr, csr_src, dis, hsA, hsB, N);
    // layer-1 aggregate (output premultiplied by dis for layer-2 GEMM)
    k_agg_ln<true><<<nbA, 256, 0, stream>>>(hsA, hsB, rr, csr_src, dis,
                                            b0, g0, be0, (void*)h1A, (void*)h1B, N);
    // layer-2 GEMM (input premultiplied => output correctly scaled)
    k_gemm2<<<nbG, 256, 0, stream>>>((const ushort_t*)h1A, (const ushort_t*)h1B, W1,
                                     (ushort_t*)hsA, (ushort_t*)hsB, N);
    // layer-2 aggregate -> final f32 output
    k_agg_ln<false><<<nbA, 256, 0, stream>>>(hsA, hsB, rr, csr_src, dis,
                                             b1, g1, be1, (void*)outf, nullptr, N);
}